// Round 1
// baseline (451.553 us; speedup 1.0000x reference)
//
#include <hip/hip_runtime.h>
#include <hip/hip_bf16.h>
#include <stdint.h>

typedef __attribute__((ext_vector_type(8))) short short8;
typedef __attribute__((ext_vector_type(4))) float f32x4;

__device__ inline unsigned short f2bf(float f) {
    union { float f; uint32_t u; } v; v.f = f;
    uint32_t u = v.u;
    uint32_t r = (u + 0x7FFFu + ((u >> 16) & 1u)) >> 16;   // RNE
    return (unsigned short)r;
}

__device__ inline short8 pk8(float4 a, float4 b) {
    short8 r;
    r[0] = (short)f2bf(a.x); r[1] = (short)f2bf(a.y);
    r[2] = (short)f2bf(a.z); r[3] = (short)f2bf(a.w);
    r[4] = (short)f2bf(b.x); r[5] = (short)f2bf(b.y);
    r[6] = (short)f2bf(b.z); r[7] = (short)f2bf(b.w);
    return r;
}

// ---------------- Router kernel 1: partial GEMM  h_pre = g_in @ W1 -------------
// grid (4 j_chunks, 64 k_splits), 256 threads. Each thread: 2 j's, all 64 b.
// W1 element read exactly once across the grid.
__global__ __launch_bounds__(256) void router1(const float* __restrict__ DKP,
                                               const float* __restrict__ W1,
                                               float* __restrict__ part) {
    __shared__ float gin[64 * 64];
    const int t  = threadIdx.x;
    const int jc = blockIdx.x;
    const int ks = blockIdx.y;
    const int k0 = ks * 64;
    {   // stage g_in chunk [64 b][64 k] (k < 4096 only; k==4096 handled in router2)
        const int b = t >> 2, q = t & 3;
        const float* src = DKP + (size_t)b * 4096 + k0 + q * 16;
        float* dst = gin + b * 64 + q * 16;
        #pragma unroll
        for (int s = 0; s < 4; ++s)
            *(float4*)(dst + 4 * s) = *(const float4*)(src + 4 * s);
    }
    __syncthreads();
    const int ja = jc * 512 + t, jb = ja + 256;
    float accA[64], accB[64];
    #pragma unroll
    for (int b = 0; b < 64; ++b) { accA[b] = 0.f; accB[b] = 0.f; }
    #pragma unroll 1
    for (int oct = 0; oct < 8; ++oct) {
        const int kk = oct * 8;
        float wa[8], wb[8];
        #pragma unroll
        for (int i = 0; i < 8; ++i) {
            const float* wr = W1 + (size_t)(k0 + kk + i) * 2048;
            wa[i] = wr[ja]; wb[i] = wr[jb];
        }
        #pragma unroll
        for (int b = 0; b < 64; ++b) {
            float4 g0 = *(const float4*)(gin + b * 64 + kk);
            float4 g1 = *(const float4*)(gin + b * 64 + kk + 4);
            accA[b] += g0.x*wa[0] + g0.y*wa[1] + g0.z*wa[2] + g0.w*wa[3]
                     + g1.x*wa[4] + g1.y*wa[5] + g1.z*wa[6] + g1.w*wa[7];
            accB[b] += g0.x*wb[0] + g0.y*wb[1] + g0.z*wb[2] + g0.w*wb[3]
                     + g1.x*wb[4] + g1.y*wb[5] + g1.z*wb[6] + g1.w*wb[7];
        }
    }
    #pragma unroll 1
    for (int b = 0; b < 64; ++b) {
        part[((size_t)ks * 64 + b) * 2048 + ja] = accA[b];
        part[((size_t)ks * 64 + b) * 2048 + jb] = accB[b];
    }
}

// ---------------- Router kernel 2: reduce splits + cycle-number col + bias + GELU
__global__ __launch_bounds__(256) void router2(const float* __restrict__ part,
                                               const float* __restrict__ cyc,
                                               const float* __restrict__ W1,
                                               const float* __restrict__ b1,
                                               float* __restrict__ h) {
    const int idx = blockIdx.x * 256 + threadIdx.x;   // idx = b*2048 + j
    const int j = idx & 2047, b = idx >> 11;
    float s = 0.f;
    #pragma unroll 8
    for (int t = 0; t < 64; ++t)
        s += part[((size_t)t * 64 + b) * 2048 + j];
    s += cyc[b] * W1[(size_t)4096 * 2048 + j] + b1[j];
    // jax.nn.gelu default (tanh approximation)
    const float u  = s + 0.044715f * s * s * s;
    const float th = tanhf(0.7978845608028654f * u);
    h[idx] = 0.5f * s * (1.0f + th);
}

// ---------------- Router kernel 3: logits, top-2, softmax, renorm gates -------
__global__ __launch_bounds__(256) void router3(const float* __restrict__ h,
                                               const float* __restrict__ W2,
                                               const float* __restrict__ b2,
                                               float4* __restrict__ gates) {
    __shared__ float red[256 * 8];
    __shared__ float lg[8];
    const int b = blockIdx.x, t = threadIdx.x;
    float acc[8];
    #pragma unroll
    for (int e = 0; e < 8; ++e) acc[e] = 0.f;
    for (int k = t; k < 2048; k += 256) {
        const float hv = h[(size_t)b * 2048 + k];
        const float* w = W2 + (size_t)k * 8;
        #pragma unroll
        for (int e = 0; e < 8; ++e) acc[e] += hv * w[e];
    }
    #pragma unroll
    for (int e = 0; e < 8; ++e) red[t * 8 + e] = acc[e];
    __syncthreads();
    if (t < 8) {
        float s = 0.f;
        for (int r = 0; r < 256; ++r) s += red[r * 8 + t];
        lg[t] = s + b2[t];
    }
    __syncthreads();
    if (t == 0) {
        float l[8];
        #pragma unroll
        for (int e = 0; e < 8; ++e) l[e] = lg[e];
        int e0 = 0;
        #pragma unroll
        for (int e = 1; e < 8; ++e) if (l[e] > l[e0]) e0 = e;
        int e1 = (e0 == 0) ? 1 : 0;
        #pragma unroll
        for (int e = 0; e < 8; ++e) if (e != e0 && l[e] > l[e1]) e1 = e;
        const float m = l[e0];
        float p[8], Z = 0.f;
        #pragma unroll
        for (int e = 0; e < 8; ++e) { p[e] = expf(l[e] - m); Z += p[e]; }
        const float pe0 = p[e0] / Z, pe1 = p[e1] / Z;
        const float s2 = pe0 + pe1 + 1e-9f;
        gates[b] = make_float4(__int_as_float(e0), __int_as_float(e1), pe0 / s2, pe1 / s2);
    }
}

// ---------------- Combine weights: Wcomb^T[b][d][i] = (genW + g0*We0 + g1*We1)^T, bf16, K-pad to 928
__global__ __launch_bounds__(256) void combine_w(const float* __restrict__ genW,
                                                 const float* __restrict__ expW,
                                                 const float4* __restrict__ gates,
                                                 unsigned short* __restrict__ wc) {
    __shared__ unsigned short T[64 * 72];   // [d_loc][i_loc], stride 72 for aligned b128 row reads
    const int b  = blockIdx.z;
    const int i0 = blockIdx.y * 64;
    const int d0 = blockIdx.x * 64;
    const float4 gt = gates[b];
    const int e0 = __float_as_int(gt.x), e1 = __float_as_int(gt.y);
    const float g0 = gt.z, g1 = gt.w;
    const float* W0 = expW + (size_t)e0 * 900 * 512;
    const float* W1e = expW + (size_t)e1 * 900 * 512;
    const int t = threadIdx.x;
    {
        const int il = t >> 2, c = t & 3;
        const int i = i0 + il;
        const bool valid = (i < 900);
        const size_t rowoff = (size_t)i * 512 + d0 + c * 16;
        #pragma unroll
        for (int s = 0; s < 4; ++s) {
            float4 g  = valid ? *(const float4*)(genW + rowoff + 4 * s) : make_float4(0,0,0,0);
            float4 w0 = valid ? *(const float4*)(W0   + rowoff + 4 * s) : make_float4(0,0,0,0);
            float4 w1 = valid ? *(const float4*)(W1e  + rowoff + 4 * s) : make_float4(0,0,0,0);
            const int dl = c * 16 + 4 * s;
            T[(dl + 0) * 72 + il] = f2bf(g.x + g0 * w0.x + g1 * w1.x);
            T[(dl + 1) * 72 + il] = f2bf(g.y + g0 * w0.y + g1 * w1.y);
            T[(dl + 2) * 72 + il] = f2bf(g.z + g0 * w0.z + g1 * w1.z);
            T[(dl + 3) * 72 + il] = f2bf(g.w + g0 * w0.w + g1 * w1.w);
        }
    }
    __syncthreads();
    {
        const int dl = t >> 2, seg = t & 3;
        const int ic = seg * 16;
        if (i0 + ic < 928) {
            short8 v0 = *(const short8*)&T[dl * 72 + ic];
            short8 v1 = *(const short8*)&T[dl * 72 + ic + 8];
            unsigned short* dst = wc + (size_t)b * 512 * 928 + (size_t)(d0 + dl) * 928 + i0 + ic;
            *(short8*)dst = v0;
            *((short8*)dst + 1) = v1;
        }
    }
}

// ---------------- Main fused batched GEMM: out[b] = x[b] @ (genW + Wb) + bias --
// 128x128 tile, BK=32, 4 waves (2x2 of 64x64), 16x16x32 bf16 MFMA.
__global__ __launch_bounds__(256, 2) void moe_gemm(const float* __restrict__ x,
                                                   const unsigned short* __restrict__ wc,
                                                   const float4* __restrict__ gates,
                                                   const float* __restrict__ eb,
                                                   const float* __restrict__ genb,
                                                   float* __restrict__ out) {
    __shared__ unsigned short As[128 * 32];   // [m][k] bf16
    __shared__ unsigned short Bs[128 * 32];   // [n][k] bf16 (B^T)
    const int b    = blockIdx.y;
    const int tile = blockIdx.x;
    const int m0 = (tile >> 2) * 128, n0 = (tile & 3) * 128;
    const int t = threadIdx.x, lane = t & 63, wid = t >> 6;
    const float4 gt = gates[b];
    const int e0 = __float_as_int(gt.x), e1 = __float_as_int(gt.y);
    const float g0 = gt.z, g1 = gt.w;
    const float* xb = x + (size_t)b * 512 * 900;
    const unsigned short* wcb = wc + (size_t)b * 512 * 928;
    f32x4 acc[4][4];
    #pragma unroll
    for (int mi = 0; mi < 4; ++mi)
        #pragma unroll
        for (int ni = 0; ni < 4; ++ni)
            acc[mi][ni] = (f32x4){0.f, 0.f, 0.f, 0.f};

    const int arow = t >> 1, ahalf = t & 1;
    const float* xrow = xb + (size_t)(m0 + arow) * 900 + ahalf * 16;
    const int wm = (wid >> 1) * 64, wn = (wid & 1) * 64;
    const int lm = lane & 15, lq = lane >> 4;

    for (int kt = 0; kt < 29; ++kt) {
        const int k0 = kt * 32;
        // ---- A stage: f32 -> bf16 via VGPRs
        short8 av0, av1;
        if (k0 + 32 <= 900) {
            float4 f0 = *(const float4*)(xrow + k0);
            float4 f1 = *(const float4*)(xrow + k0 + 4);
            float4 f2 = *(const float4*)(xrow + k0 + 8);
            float4 f3 = *(const float4*)(xrow + k0 + 12);
            av0 = pk8(f0, f1); av1 = pk8(f2, f3);
        } else {
            float v[16];
            #pragma unroll
            for (int i = 0; i < 16; ++i) {
                const int k = k0 + ahalf * 16 + i;
                v[i] = (k < 900) ? xrow[k0 + i] : 0.f;
            }
            float4 f0 = make_float4(v[0], v[1], v[2], v[3]);
            float4 f1 = make_float4(v[4], v[5], v[6], v[7]);
            float4 f2 = make_float4(v[8], v[9], v[10], v[11]);
            float4 f3 = make_float4(v[12], v[13], v[14], v[15]);
            av0 = pk8(f0, f1); av1 = pk8(f2, f3);
        }
        // ---- B stage: async global->LDS, width 16
        #pragma unroll
        for (int r = 0; r < 2; ++r) {
            const int chunk = wid * 2 + r;
            const int lin = chunk * 64 + lane;
            const int n = lin >> 2, seg = lin & 3;
            const unsigned short* gsrc = wcb + (size_t)(n0 + n) * 928 + k0 + seg * 8;
            unsigned short* ldst = &Bs[chunk * 512];
            __builtin_amdgcn_global_load_lds(
                (const __attribute__((address_space(1))) unsigned int*)gsrc,
                (__attribute__((address_space(3))) unsigned int*)ldst, 16, 0, 0);
        }
        *(short8*)&As[arow * 32 + ahalf * 16]     = av0;
        *(short8*)&As[arow * 32 + ahalf * 16 + 8] = av1;
        __syncthreads();
        // ---- MFMA
        short8 af[4], bf[4];
        #pragma unroll
        for (int mi = 0; mi < 4; ++mi)
            af[mi] = *(const short8*)&As[(wm + mi * 16 + lm) * 32 + lq * 8];
        #pragma unroll
        for (int ni = 0; ni < 4; ++ni)
            bf[ni] = *(const short8*)&Bs[(wn + ni * 16 + lm) * 32 + lq * 8];
        #pragma unroll
        for (int mi = 0; mi < 4; ++mi)
            #pragma unroll
            for (int ni = 0; ni < 4; ++ni)
                acc[mi][ni] = __builtin_amdgcn_mfma_f32_16x16x32_bf16(
                    af[mi], bf[ni], acc[mi][ni], 0, 0, 0);
        __syncthreads();
    }
    // ---- Epilogue: add gen_b + g0*eb[e0] + g1*eb[e1], store f32
    #pragma unroll
    for (int ni = 0; ni < 4; ++ni) {
        const int col = n0 + wn + ni * 16 + lm;
        const float bias = genb[col] + g0 * eb[e0 * 512 + col] + g1 * eb[e1 * 512 + col];
        #pragma unroll
        for (int mi = 0; mi < 4; ++mi) {
            const int row = m0 + wm + mi * 16 + lq * 4;
            #pragma unroll
            for (int r = 0; r < 4; ++r)
                out[((size_t)b * 512 + row + r) * 512 + col] = acc[mi][ni][r] + bias;
        }
    }
}

extern "C" void kernel_launch(void* const* d_in, const int* in_sizes, int n_in,
                              void* d_out, int out_size, void* d_ws, size_t ws_size,
                              hipStream_t stream) {
    const float* x    = (const float*)d_in[0];   // [64][512][900] (3*300 flattened)
    const float* cyc  = (const float*)d_in[1];   // [64][1]
    const float* dkp  = (const float*)d_in[2];   // [64][4096]
    const float* gW1  = (const float*)d_in[3];   // [4097][2048]
    const float* gb1  = (const float*)d_in[4];   // [2048]
    const float* gW2  = (const float*)d_in[5];   // [2048][8]
    const float* gb2  = (const float*)d_in[6];   // [8]
    const float* eW   = (const float*)d_in[7];   // [8][900][512]
    const float* eb   = (const float*)d_in[8];   // [8][512]
    const float* genW = (const float*)d_in[9];   // [900][512]
    const float* genb = (const float*)d_in[10];  // [512]
    float* out = (float*)d_out;                  // [64][512][512] f32

    char* ws = (char*)d_ws;
    // ws layout: [0, 60817408): Wcomb bf16 [64][512][928]; partials (33.5MB) alias
    // this region (dead before combine_w runs). Then h (512KB), gates (1KB).
    unsigned short* wcomb = (unsigned short*)ws;
    float* part  = (float*)ws;                          // [64][64][2048] f32
    float* h     = (float*)(ws + 60817408);             // [64][2048] f32
    float4* gts  = (float4*)(ws + 60817408 + 524288);   // [64] {e0,e1,g0,g1}

    router1<<<dim3(4, 64), 256, 0, stream>>>(dkp, gW1, part);
    router2<<<512, 256, 0, stream>>>(part, cyc, gW1, gb1, h);
    router3<<<64, 256, 0, stream>>>(h, gW2, gb2, gts);
    combine_w<<<dim3(8, 15, 64), 256, 0, stream>>>(genW, eW, gts, wcomb);
    moe_gemm<<<dim3(16, 64), 256, 0, stream>>>(x, wcomb, gts, eb, genb, out);
}

// Round 2
// 400.042 us; speedup vs baseline: 1.1288x; 1.1288x over previous
//
#include <hip/hip_runtime.h>
#include <hip/hip_bf16.h>
#include <stdint.h>

typedef __attribute__((ext_vector_type(8))) short short8;
typedef __attribute__((ext_vector_type(4))) short short4v;
typedef __attribute__((ext_vector_type(4))) float f32x4;

__device__ inline unsigned short f2bf(float f) {
    union { float f; uint32_t u; } v; v.f = f;
    uint32_t u = v.u;
    uint32_t r = (u + 0x7FFFu + ((u >> 16) & 1u)) >> 16;   // RNE
    return (unsigned short)r;
}

__device__ inline short4v pk4(float4 a) {
    short4v r;
    r[0] = (short)f2bf(a.x); r[1] = (short)f2bf(a.y);
    r[2] = (short)f2bf(a.z); r[3] = (short)f2bf(a.w);
    return r;
}

// ---------------- Router kernel 1: partial GEMM  h_pre = g_in @ W1 -------------
// grid (16, 64): x = bg(4, fastest — shares W1 slice with neighbors via L2) + 4*jc,
// y = ks (64 k-splits of 64). Each thread: 2 j's, 16 batteries -> 32 accumulators
// (NO spill; R0 version had 128 acc -> 326 MB scratch traffic).
__global__ __launch_bounds__(256) void router1(const float* __restrict__ DKP,
                                               const float* __restrict__ W1,
                                               float* __restrict__ part) {
    __shared__ float gin[16 * 64];
    const int t  = threadIdx.x;
    const int bg = blockIdx.x & 3, jc = blockIdx.x >> 2;
    const int ks = blockIdx.y;
    const int k0 = ks * 64;
    {   // stage g_in chunk [16 b][64 k]
        const int b = t >> 4, q = t & 15;
        *(float4*)(gin + b * 64 + q * 4) =
            *(const float4*)(DKP + (size_t)(bg * 16 + b) * 4096 + k0 + q * 4);
    }
    __syncthreads();
    const int ja = jc * 512 + t, jb = ja + 256;
    float accA[16], accB[16];
    #pragma unroll
    for (int b = 0; b < 16; ++b) { accA[b] = 0.f; accB[b] = 0.f; }
    #pragma unroll 1
    for (int oct = 0; oct < 8; ++oct) {
        const int kk = oct * 8;
        float wa[8], wb[8];
        #pragma unroll
        for (int i = 0; i < 8; ++i) {
            const float* wr = W1 + (size_t)(k0 + kk + i) * 2048;
            wa[i] = wr[ja]; wb[i] = wr[jb];
        }
        #pragma unroll
        for (int b = 0; b < 16; ++b) {
            float4 g0 = *(const float4*)(gin + b * 64 + kk);
            float4 g1 = *(const float4*)(gin + b * 64 + kk + 4);
            accA[b] += g0.x*wa[0] + g0.y*wa[1] + g0.z*wa[2] + g0.w*wa[3]
                     + g1.x*wa[4] + g1.y*wa[5] + g1.z*wa[6] + g1.w*wa[7];
            accB[b] += g0.x*wb[0] + g0.y*wb[1] + g0.z*wb[2] + g0.w*wb[3]
                     + g1.x*wb[4] + g1.y*wb[5] + g1.z*wb[6] + g1.w*wb[7];
        }
    }
    #pragma unroll 1
    for (int b = 0; b < 16; ++b) {
        const size_t row = (size_t)(ks * 64 + bg * 16 + b) * 2048;
        part[row + ja] = accA[b];
        part[row + jb] = accB[b];
    }
}

// ---------------- Router kernel 2: reduce splits + cycle-number col + bias + GELU
__global__ __launch_bounds__(256) void router2(const float* __restrict__ part,
                                               const float* __restrict__ cyc,
                                               const float* __restrict__ W1,
                                               const float* __restrict__ b1,
                                               float* __restrict__ h) {
    const int idx = blockIdx.x * 256 + threadIdx.x;   // idx = b*2048 + j
    const int j = idx & 2047, b = idx >> 11;
    float s = 0.f;
    #pragma unroll 8
    for (int t = 0; t < 64; ++t)
        s += part[((size_t)t * 64 + b) * 2048 + j];
    s += cyc[b] * W1[(size_t)4096 * 2048 + j] + b1[j];
    // jax.nn.gelu default (tanh approximation)
    const float u  = s + 0.044715f * s * s * s;
    const float th = tanhf(0.7978845608028654f * u);
    h[idx] = 0.5f * s * (1.0f + th);
}

// ---------------- Router kernel 3: logits, top-2, softmax, renorm gates -------
__global__ __launch_bounds__(256) void router3(const float* __restrict__ h,
                                               const float* __restrict__ W2,
                                               const float* __restrict__ b2,
                                               float4* __restrict__ gates) {
    __shared__ float red[256 * 8];
    __shared__ float lg[8];
    const int b = blockIdx.x, t = threadIdx.x;
    float acc[8];
    #pragma unroll
    for (int e = 0; e < 8; ++e) acc[e] = 0.f;
    for (int k = t; k < 2048; k += 256) {
        const float hv = h[(size_t)b * 2048 + k];
        const float* w = W2 + (size_t)k * 8;
        #pragma unroll
        for (int e = 0; e < 8; ++e) acc[e] += hv * w[e];
    }
    #pragma unroll
    for (int e = 0; e < 8; ++e) red[t * 8 + e] = acc[e];
    __syncthreads();
    if (t < 8) {
        float s = 0.f;
        for (int r = 0; r < 256; ++r) s += red[r * 8 + t];
        lg[t] = s + b2[t];
    }
    __syncthreads();
    if (t == 0) {
        float l[8];
        #pragma unroll
        for (int e = 0; e < 8; ++e) l[e] = lg[e];
        int e0 = 0;
        #pragma unroll
        for (int e = 1; e < 8; ++e) if (l[e] > l[e0]) e0 = e;
        int e1 = (e0 == 0) ? 1 : 0;
        #pragma unroll
        for (int e = 0; e < 8; ++e) if (e != e0 && l[e] > l[e1]) e1 = e;
        const float m = l[e0];
        float p[8], Z = 0.f;
        #pragma unroll
        for (int e = 0; e < 8; ++e) { p[e] = expf(l[e] - m); Z += p[e]; }
        const float pe0 = p[e0] / Z, pe1 = p[e1] / Z;
        const float s2 = pe0 + pe1 + 1e-9f;
        gates[b] = make_float4(__int_as_float(e0), __int_as_float(e1), pe0 / s2, pe1 / s2);
    }
}

// ---------------- Combine weights: Wcomb^T[b][d][i] = (genW + g0*We0 + g1*We1)^T, bf16, K-pad to 928
__global__ __launch_bounds__(256) void combine_w(const float* __restrict__ genW,
                                                 const float* __restrict__ expW,
                                                 const float4* __restrict__ gates,
                                                 unsigned short* __restrict__ wc) {
    __shared__ unsigned short T[64 * 72];   // [d_loc][i_loc], stride 72 for aligned b128 row reads
    const int b  = blockIdx.z;
    const int i0 = blockIdx.y * 64;
    const int d0 = blockIdx.x * 64;
    const float4 gt = gates[b];
    const int e0 = __float_as_int(gt.x), e1 = __float_as_int(gt.y);
    const float g0 = gt.z, g1 = gt.w;
    const float* W0 = expW + (size_t)e0 * 900 * 512;
    const float* W1e = expW + (size_t)e1 * 900 * 512;
    const int t = threadIdx.x;
    {
        const int il = t >> 2, c = t & 3;
        const int i = i0 + il;
        const bool valid = (i < 900);
        const size_t rowoff = (size_t)i * 512 + d0 + c * 16;
        #pragma unroll
        for (int s = 0; s < 4; ++s) {
            float4 g  = valid ? *(const float4*)(genW + rowoff + 4 * s) : make_float4(0,0,0,0);
            float4 w0 = valid ? *(const float4*)(W0   + rowoff + 4 * s) : make_float4(0,0,0,0);
            float4 w1 = valid ? *(const float4*)(W1e  + rowoff + 4 * s) : make_float4(0,0,0,0);
            const int dl = c * 16 + 4 * s;
            T[(dl + 0) * 72 + il] = f2bf(g.x + g0 * w0.x + g1 * w1.x);
            T[(dl + 1) * 72 + il] = f2bf(g.y + g0 * w0.y + g1 * w1.y);
            T[(dl + 2) * 72 + il] = f2bf(g.z + g0 * w0.z + g1 * w1.z);
            T[(dl + 3) * 72 + il] = f2bf(g.w + g0 * w0.w + g1 * w1.w);
        }
    }
    __syncthreads();
    {
        const int dl = t >> 2, seg = t & 3;
        const int ic = seg * 16;
        if (i0 + ic < 928) {
            short8 v0 = *(const short8*)&T[dl * 72 + ic];
            short8 v1 = *(const short8*)&T[dl * 72 + ic + 8];
            unsigned short* dst = wc + (size_t)b * 512 * 928 + (size_t)(d0 + dl) * 928 + i0 + ic;
            *(short8*)dst = v0;
            *((short8*)dst + 1) = v1;
        }
    }
}

// ---------------- Main fused batched GEMM: out[b] = x[b] @ Wcomb_b + bias ------
// Tile 64m x 512n (FULL d) per block, 512 threads = 8 waves (each wave 64x64),
// BK=32, 16x16x32 bf16 MFMA. grid (64 b, 8 m): linear%8 = b%8 -> all of battery
// b's blocks land on one XCD (wcomb_b L2-resident); x fetched exactly once.
// As padded to 40 shorts/row (2-way banks = free); Bs slot-XOR-swizzled so
// ds_read_b128 fragments are 2-way instead of 8-way (R1 had 5.7M conflict cy).
__global__ __launch_bounds__(512, 4) void moe_gemm(const float* __restrict__ x,
                                                   const unsigned short* __restrict__ wc,
                                                   const float4* __restrict__ gates,
                                                   const float* __restrict__ eb,
                                                   const float* __restrict__ genb,
                                                   float* __restrict__ out) {
    __shared__ unsigned short As[64 * 40];    // [m][k] bf16, padded stride 40
    __shared__ unsigned short Bs[512 * 32];   // [n][k] bf16, rows 64B contiguous, slots swizzled
    const int b  = blockIdx.x;
    const int m0 = blockIdx.y * 64;
    const int t = threadIdx.x, lane = t & 63, wid = t >> 6;
    const float4 gt = gates[b];
    const int e0 = __float_as_int(gt.x), e1 = __float_as_int(gt.y);
    const float g0 = gt.z, g1 = gt.w;
    const float* xb = x + (size_t)b * 512 * 900;
    const unsigned short* wcb = wc + (size_t)b * 512 * 928;
    f32x4 acc[4][4];
    #pragma unroll
    for (int mi = 0; mi < 4; ++mi)
        #pragma unroll
        for (int ni = 0; ni < 4; ++ni)
            acc[mi][ni] = (f32x4){0.f, 0.f, 0.f, 0.f};

    // A staging: thread -> (row = t>>3, 4 floats at (t&7)*4)
    const int arow  = t >> 3;
    const int akoff = (t & 7) * 4;
    const float* xrow = xb + (size_t)(m0 + arow) * 900 + akoff;
    // B staging: lane -> row u=lane>>2 within 16-row chunk; slot=lane&3 holds
    // global seg = slot ^ ((n>>1)&3) = slot ^ ((lane>>3)&3)
    const int bseg = (lane & 3) ^ ((lane >> 3) & 3);
    const int burow = lane >> 2;

    const int wn = wid * 64;
    const int lm = lane & 15, lq = lane >> 4;

    for (int kt = 0; kt < 29; ++kt) {
        const int k0 = kt * 32;
        // ---- B: async global->LDS, 4 chunks of 16 rows per wave
        #pragma unroll
        for (int r = 0; r < 4; ++r) {
            const int chunk = wid * 4 + r;
            const int n = chunk * 16 + burow;
            const unsigned short* gsrc = wcb + (size_t)n * 928 + k0 + bseg * 8;
            unsigned short* ldst = &Bs[chunk * 512];
            __builtin_amdgcn_global_load_lds(
                (const __attribute__((address_space(1))) unsigned int*)gsrc,
                (__attribute__((address_space(3))) unsigned int*)ldst, 16, 0, 0);
        }
        // ---- A: 4 floats -> bf16x4 -> LDS
        float4 f;
        if (k0 + 32 <= 900) {
            f = *(const float4*)(xrow + k0);
        } else {
            float v[4];
            #pragma unroll
            for (int i = 0; i < 4; ++i) {
                const int k = k0 + akoff + i;
                v[i] = (k < 900) ? xrow[k0 + i] : 0.f;
            }
            f = make_float4(v[0], v[1], v[2], v[3]);
        }
        *(short4v*)&As[arow * 40 + akoff] = pk4(f);
        __syncthreads();
        // ---- fragments + MFMA
        short8 af[4], bf[4];
        #pragma unroll
        for (int mi = 0; mi < 4; ++mi)
            af[mi] = *(const short8*)&As[(mi * 16 + lm) * 40 + lq * 8];
        #pragma unroll
        for (int ni = 0; ni < 4; ++ni) {
            const int n = wn + ni * 16 + lm;
            const int slot = lq ^ ((lm >> 1) & 3);
            bf[ni] = *(const short8*)&Bs[n * 32 + slot * 8];
        }
        #pragma unroll
        for (int mi = 0; mi < 4; ++mi)
            #pragma unroll
            for (int ni = 0; ni < 4; ++ni)
                acc[mi][ni] = __builtin_amdgcn_mfma_f32_16x16x32_bf16(
                    af[mi], bf[ni], acc[mi][ni], 0, 0, 0);
        __syncthreads();
    }
    // ---- Epilogue: add gen_b + g0*eb[e0] + g1*eb[e1], store f32
    #pragma unroll
    for (int ni = 0; ni < 4; ++ni) {
        const int col = wn + ni * 16 + lm;
        const float bias = genb[col] + g0 * eb[e0 * 512 + col] + g1 * eb[e1 * 512 + col];
        #pragma unroll
        for (int mi = 0; mi < 4; ++mi) {
            const int row = m0 + mi * 16 + lq * 4;
            #pragma unroll
            for (int r = 0; r < 4; ++r)
                out[((size_t)b * 512 + row + r) * 512 + col] = acc[mi][ni][r] + bias;
        }
    }
}

extern "C" void kernel_launch(void* const* d_in, const int* in_sizes, int n_in,
                              void* d_out, int out_size, void* d_ws, size_t ws_size,
                              hipStream_t stream) {
    const float* x    = (const float*)d_in[0];   // [64][512][900]
    const float* cyc  = (const float*)d_in[1];   // [64][1]
    const float* dkp  = (const float*)d_in[2];   // [64][4096]
    const float* gW1  = (const float*)d_in[3];   // [4097][2048]
    const float* gb1  = (const float*)d_in[4];   // [2048]
    const float* gW2  = (const float*)d_in[5];   // [2048][8]
    const float* gb2  = (const float*)d_in[6];   // [8]
    const float* eW   = (const float*)d_in[7];   // [8][900][512]
    const float* eb   = (const float*)d_in[8];   // [8][512]
    const float* genW = (const float*)d_in[9];   // [900][512]
    const float* genb = (const float*)d_in[10];  // [512]
    float* out = (float*)d_out;                  // [64][512][512] f32

    char* ws = (char*)d_ws;
    // ws layout: [0, 60817408): Wcomb bf16 [64][512][928]; partials (33.5MB) alias
    // this region (dead before combine_w runs). Then h (512KB), gates (1KB).
    unsigned short* wcomb = (unsigned short*)ws;
    float* part  = (float*)ws;                          // [64][64][2048] f32
    float* h     = (float*)(ws + 60817408);             // [64][2048] f32
    float4* gts  = (float4*)(ws + 60817408 + 524288);   // [64] {e0,e1,g0,g1}

    router1<<<dim3(16, 64), 256, 0, stream>>>(dkp, gW1, part);
    router2<<<512, 256, 0, stream>>>(part, cyc, gW1, gb1, h);
    router3<<<64, 256, 0, stream>>>(h, gW2, gb2, gts);
    combine_w<<<dim3(8, 15, 64), 256, 0, stream>>>(genW, eW, gts, wcomb);
    moe_gemm<<<dim3(64, 8), 512, 0, stream>>>(x, wcomb, gts, eb, genb, out);
}